// Round 6
// baseline (376.354 us; speedup 1.0000x reference)
//
#include <hip/hip_runtime.h>
#include <hip/hip_bf16.h>

#define NT 1024     // tokens (B*S)
#define HD 1024     // hidden
#define ED 1024     // expert inner dim
#define F2D 2048    // 2*E (interleaved gate/up)
#define NEXPERT 16
#define GROWS 2304  // compacted rows (2048) + tile slack (gemm reads up to base+255 <= 2303)
#define ALPHA_C 1.702f
#define LIMIT_C 7.0f

typedef float f32x4 __attribute__((ext_vector_type(4)));
typedef float fv4 __attribute__((ext_vector_type(4)));
typedef short short8 __attribute__((ext_vector_type(8)));
typedef unsigned int u32x4 __attribute__((ext_vector_type(4)));

__device__ __forceinline__ unsigned short f2bf(float x) {
  union { float f; unsigned int u; } v; v.f = x;
  unsigned int r = v.u + 0x7FFFu + ((v.u >> 16) & 1u);
  return (unsigned short)(r >> 16);
}
__device__ __forceinline__ unsigned int pk2(float lo, float hi) {
  return (unsigned int)f2bf(lo) | ((unsigned int)f2bf(hi) << 16);
}
// non-temporal float4 load (weights: stream, don't cache)
__device__ __forceinline__ fv4 ldnt4(const float* p) {
  return __builtin_nontemporal_load((const fv4*)p);
}
// async global->LDS, 16B per lane; LDS dest = wave-uniform base + lane*16
__device__ __forceinline__ void async16(const void* g, void* l) {
  __builtin_amdgcn_global_load_lds((const __attribute__((address_space(1))) void*)g,
                                   (__attribute__((address_space(3))) void*)l, 16, 0, 0);
}

// in-quad 4x4 transpose (XOR network via DPP quad_perm) + b128 LDS store.
// requires: b0,b1 (fv4 weight rows k=2*kpair, 2*kpair+1), sub = lane&3 in scope.
// verified correct in rounds 4/5 (passing absmax).
#define BT_TRANSPOSE_STORE(DST)                                                         \
  {                                                                                     \
    unsigned int w0p = pk2(b0[0], b1[0]);                                               \
    unsigned int w1p = pk2(b0[1], b1[1]);                                               \
    unsigned int w2p = pk2(b0[2], b1[2]);                                               \
    unsigned int w3p = pk2(b0[3], b1[3]);                                               \
    unsigned int X0 = sub == 0 ? w0p : sub == 1 ? w1p : sub == 2 ? w2p : w3p;           \
    unsigned int X1 = sub == 0 ? w1p : sub == 1 ? w0p : sub == 2 ? w3p : w2p;           \
    unsigned int X2 = sub == 0 ? w2p : sub == 1 ? w3p : sub == 2 ? w0p : w1p;           \
    unsigned int X3 = sub == 0 ? w3p : sub == 1 ? w2p : sub == 2 ? w1p : w0p;           \
    unsigned int r0 = X0;                                                               \
    unsigned int r1 = (unsigned int)__builtin_amdgcn_update_dpp((int)X1, (int)X1, 0xB1, 0xF, 0xF, 0); \
    unsigned int r2 = (unsigned int)__builtin_amdgcn_update_dpp((int)X2, (int)X2, 0x4E, 0xF, 0xF, 0); \
    unsigned int r3 = (unsigned int)__builtin_amdgcn_update_dpp((int)X3, (int)X3, 0x1B, 0xF, 0xF, 0); \
    u32x4 tt;                                                                           \
    tt[0] = sub == 0 ? r0 : sub == 1 ? r1 : sub == 2 ? r2 : r3;                         \
    tt[1] = sub == 0 ? r1 : sub == 1 ? r0 : sub == 2 ? r3 : r2;                         \
    tt[2] = sub == 0 ? r2 : sub == 1 ? r3 : sub == 2 ? r0 : r1;                         \
    tt[3] = sub == 0 ? r3 : sub == 1 ? r2 : sub == 2 ? r1 : r0;                         \
    *(u32x4*)(DST) = tt;                                                                \
  }

// ---------------- router: 4 waves/token; partial logits per wave, LDS reduce, redundant top-2 ----------------
__global__ __launch_bounds__(256) void k_router(const float* __restrict__ x,
                                                const float* __restrict__ Wg,
                                                const float* __restrict__ bg,
                                                const float* __restrict__ bd,
                                                int* __restrict__ e01,
                                                float* __restrict__ w0f,
                                                float* __restrict__ w1f,
                                                unsigned short* __restrict__ Xbf,
                                                float* __restrict__ out) {
  const int t = blockIdx.x;
  const int tid = threadIdx.x;     // 0..255
  const int w = tid >> 6;          // wave 0..3 (quarter of HD)
  const int l = tid & 63;
  const float4* x4 = (const float4*)(x + (size_t)t * HD);
  // bf16 conversion: one float4 per thread
  {
    float4 v = x4[tid];
    unsigned int* dst = (unsigned int*)(Xbf + (size_t)t * HD + tid * 4);
    dst[0] = pk2(v.x, v.y); dst[1] = pk2(v.z, v.w);
  }
  // partial logits: expert e = l&15, sub-chunk qq = l>>4; wave w covers float4 idx w*64..w*64+63
  const int e = l & 15, qq = l >> 4;
  const float4* wg4 = (const float4*)(Wg + (size_t)e * HD);
  float s = 0.f;
#pragma unroll 4
  for (int j = 0; j < 16; ++j) {
    const int idx = w * 64 + qq + 4 * j;
    float4 a = x4[idx], b = wg4[idx];
    s += a.x * b.x + a.y * b.y + a.z * b.z + a.w * b.w;
  }
  s += __shfl_xor(s, 16);
  s += __shfl_xor(s, 32);          // lanes 0..15 hold quarter-partial for expert e
  __shared__ float slog[4][16];
  if (l < 16) slog[w][e] = s;
  __syncthreads();
  // all threads: full logits + top2 (redundant, deterministic)
  float v0 = -1e30f, v1 = -1e30f; int i0 = 0, i1 = 0;
  for (int k2 = 0; k2 < 16; ++k2) {
    float lv = slog[0][k2] + slog[1][k2] + slog[2][k2] + slog[3][k2] + bg[k2];
    if (lv > v0) { v1 = v0; i1 = i0; v0 = lv; i0 = k2; }
    else if (lv > v1) { v1 = lv; i1 = k2; }
  }
  const float w0 = 1.f / (1.f + __expf(v1 - v0));
  const float w1 = 1.f - w0;
  if (tid == 0) {
    e01[t] = i0 | (i1 << 8);
    w0f[t] = w0;
    w1f[t] = w1;
  }
  // bd premix: one float4 per thread
  const float4* bd0 = (const float4*)(bd + (size_t)i0 * HD);
  const float4* bd1 = (const float4*)(bd + (size_t)i1 * HD);
  float4 a = bd0[tid], b = bd1[tid];
  float4 r;
  r.x = w0 * a.x + w1 * b.x;
  r.y = w0 * a.y + w1 * b.y;
  r.z = w0 * a.z + w1 * b.z;
  r.w = w0 * a.w + w1 * b.w;
  ((float4*)(out + (size_t)t * HD))[tid] = r;
}

// ---------------- scan: counts, offsets, placement (one block) ----------------
__global__ __launch_bounds__(1024) void k_scan(const int* __restrict__ e01,
                                               const float* __restrict__ w0f,
                                               const float* __restrict__ w1f,
                                               int* __restrict__ cnt,
                                               int* __restrict__ off,
                                               int* __restrict__ gtok,
                                               float* __restrict__ gwt) {
  __shared__ int scnt[NEXPERT];
  __shared__ int soff[NEXPERT];
  __shared__ int scur[NEXPERT];
  const int t = threadIdx.x;
  if (t < NEXPERT) { scnt[t] = 0; scur[t] = 0; }
  __syncthreads();
  const int p = e01[t];
  const int e0 = p & 255, e1 = p >> 8;
  atomicAdd(&scnt[e0], 1);
  atomicAdd(&scnt[e1], 1);
  __syncthreads();
  if (t == 0) {
    int a = 0;
    for (int e = 0; e < NEXPERT; ++e) { soff[e] = a; off[e] = a; cnt[e] = scnt[e]; a += scnt[e]; }
  }
  __syncthreads();
  int s0 = atomicAdd(&scur[e0], 1);
  gtok[soff[e0] + s0] = t; gwt[soff[e0] + s0] = w0f[t];
  int s1 = atomicAdd(&scur[e1], 1);
  gtok[soff[e1] + s1] = t; gwt[soff[e1] + s1] = w1f[t];
}

// ---------------- GEMM1: block 256M x 64N, 256 thr (4 waves x 64 rows), BK=32, dbuf ----------------
// grid (32 ntiles, 2 mtiles, 16 experts) -> ~512 WORKING blocks = 2/CU (occupancy fix: Ne~128
// means only mtile0 runs; previous 128-col tiles gave 256 working blocks = 1/CU, latency-exposed).
// B transposed in LDS [col][kpair] stride 16 dwords: B-fragment = one ds_read_b128.
__global__ __launch_bounds__(256) void k_gemm1(const unsigned short* __restrict__ Xbf,
                                               const float* __restrict__ Wgu,
                                               const float* __restrict__ bgu,
                                               const int* __restrict__ cnt,
                                               const int* __restrict__ off,
                                               const int* __restrict__ gtok,
                                               unsigned short* __restrict__ Gact) {
  const int e = blockIdx.z;
  const int Ne = cnt[e];
  const int mtile = blockIdx.y;
  if (mtile * 256 >= Ne) return;
  const int ntile = blockIdx.x;         // 0..31, 64 cols each
  const int tid = threadIdx.x;          // 0..255
  const int lane = tid & 63;
  const int wv = tid >> 6;              // 0..3 (M 64-slice)
  const int q = lane >> 4;
  const int fr = lane & 15;
  const int base = off[e] + mtile * 256;

  __shared__ unsigned short Alds[2][256 * 32];   // [buf][row*32 + k]  32 KB
  __shared__ unsigned int Blds[2][64 * 16];      // transposed [col][kpair] 8 KB

  // A staging: thread stages rows (tid>>2) + j*64 (j=0..3), 16B chunk (tid&3)
  const int arow = tid >> 2;
  const unsigned short* agp[4];
#pragma unroll
  for (int j = 0; j < 4; ++j) {
    const int r = arow + j * 64;
    const int ags = base + (((mtile * 256 + r) < Ne) ? r : 0);
    agp[j] = Xbf + (size_t)gtok[ags] * HD + (tid & 3) * 8;
  }
  const int aofs = tid * 8;   // shorts; + j*2048

  // B staging: sub = tid&3, quad = tid>>2: colgrp = quad&15 (0..15), kblock = quad>>4 (0..3)
  // thread loads kpair kblock*4+sub, cols colgrp*4..+3; post-transpose writes col colgrp*4+sub.
  const int sub = tid & 3;
  const int quad = tid >> 2;
  const int colgrp = quad & 15;
  const int kblock = quad >> 4;
  const float* Wb = Wgu + (size_t)e * HD * F2D + (size_t)(2 * (kblock * 4 + sub)) * F2D + ntile * 64 + colgrp * 4;
  const int bofs = (colgrp * 4 + sub) * 16 + kblock * 4;   // dword offset of b128 store

  f32x4 acc[4][4] = {};
  fv4 b0, b1;

  // prologue: stage tile 0
  b0 = ldnt4(Wb);
  b1 = ldnt4(Wb + F2D);
#pragma unroll
  for (int j = 0; j < 4; ++j)
    async16(agp[j], Alds[0] + aofs + j * 2048);
  BT_TRANSPOSE_STORE(Blds[0] + bofs)
  __syncthreads();

  for (int ks = 0; ks < 32; ++ks) {
    const int cur = ks & 1, nxt = cur ^ 1;
    const bool more = (ks + 1) < 32;
    if (more) {
      const float* bp = Wb + (size_t)(ks + 1) * 32 * F2D;
      b0 = ldnt4(bp);
      b1 = ldnt4(bp + F2D);
#pragma unroll
      for (int j = 0; j < 4; ++j)
        async16(agp[j] + (ks + 1) * 32, Alds[nxt] + aofs + j * 2048);
    }
    short8 af[4], bfr[4];
#pragma unroll
    for (int mi = 0; mi < 4; ++mi)
      af[mi] = *(const short8*)(Alds[cur] + (wv * 64 + mi * 16 + fr) * 32 + q * 8);
#pragma unroll
    for (int ni = 0; ni < 4; ++ni)
      bfr[ni] = *(const short8*)(Blds[cur] + (ni * 16 + fr) * 16 + q * 4);
#pragma unroll
    for (int mi = 0; mi < 4; ++mi)
#pragma unroll
      for (int ni = 0; ni < 4; ++ni)
        acc[mi][ni] = __builtin_amdgcn_mfma_f32_16x16x32_bf16(af[mi], bfr[ni], acc[mi][ni], 0, 0, 0);
    if (more) BT_TRANSPOSE_STORE(Blds[nxt] + bofs)
    __syncthreads();
  }

  // epilogue: +bgu, de-interleave gate/up via lane-pair shuffle, activation, store bf16
  const float* bguE = bgu + (size_t)e * F2D + ntile * 64;
#pragma unroll
  for (int mi = 0; mi < 4; ++mi) {
#pragma unroll
    for (int ni = 0; ni < 4; ++ni) {
      const int coll = ni * 16 + fr;
      const float bias = bguE[coll];
#pragma unroll
      for (int r = 0; r < 4; ++r) {
        const int srow = wv * 64 + mi * 16 + q * 4 + r;
        float v = acc[mi][ni][r] + bias;
        float pv = __shfl_xor(v, 1);
        float gate = (lane & 1) ? pv : v;   // even f2-cols are gate, odd are up
        float up   = (lane & 1) ? v : pv;
        gate = fminf(gate, LIMIT_C);
        up = fminf(fmaxf(up, -LIMIT_C), LIMIT_C);
        float glu = gate / (1.f + __expf(-ALPHA_C * gate));
        float val = (up + 1.f) * glu;
        if (!(lane & 1) && (mtile * 256 + srow) < Ne)
          Gact[(size_t)(base + srow) * ED + ((ntile * 64 + coll) >> 1)] = f2bf(val);
      }
    }
  }
}

// ---------------- GEMM2: block 256M x 32N, 256 thr (4 waves x 64 rows), BK=32 ----------------
// grid (32 ntiles, 2 mtiles, 16 experts) -> ~512 working blocks = 2/CU.
// A direct global->register with 1-step prefetch (no cross-wave A reuse; Gact L2-resident).
// B double-buffered LDS, transposed [col][kpair] stride 16 dwords. Atomic epilogue.
__global__ __launch_bounds__(256) void k_gemm2(const unsigned short* __restrict__ Gact,
                                               const float* __restrict__ Wd,
                                               const int* __restrict__ cnt,
                                               const int* __restrict__ off,
                                               const int* __restrict__ gtok,
                                               const float* __restrict__ gwt,
                                               float* __restrict__ out) {
  const int e = blockIdx.z;
  const int Ne = cnt[e];
  const int mtile = blockIdx.y;
  if (mtile * 256 >= Ne) return;
  const int ntile = blockIdx.x;         // 0..31, 32 cols each
  const int tid = threadIdx.x;          // 0..255
  const int lane = tid & 63;
  const int wv = tid >> 6;              // 0..3 (M 64-slice)
  const int q = lane >> 4;
  const int fr = lane & 15;
  const int base = off[e] + mtile * 256;

  __shared__ unsigned int Blds[2][32 * 16];    // transposed B only, 4 KB

  // A direct: lane reads rows base + wv*64 + mi*16 + fr, 16B at k-chunk q; rows <= base+255 < GROWS
  const unsigned short* agA[4];
#pragma unroll
  for (int mi = 0; mi < 4; ++mi)
    agA[mi] = Gact + (size_t)(base + wv * 64 + mi * 16 + fr) * ED + q * 8;

  // B staging (threads 0..127, waves 0-1): sub = tid&3, quad = tid>>2 (0..31):
  // colgrp = quad&7, kblock = quad>>3; loads kpair kblock*4+sub, cols colgrp*4..+3.
  const int sub = tid & 3;
  const int quad = tid >> 2;
  const int colgrp = quad & 7;
  const int kblock = quad >> 3;   // 0..3 for tid<128
  const float* Wb = Wd + (size_t)e * ED * HD + (size_t)(2 * (kblock * 4 + sub)) * HD + ntile * 32 + colgrp * 4;
  const int bofs = (colgrp * 4 + sub) * 16 + kblock * 4;

  f32x4 acc[4][2] = {};
  fv4 b0, b1;
  short8 a0, a1, a2, a3, a0n, a1n, a2n, a3n;

  if (tid < 128) {
    b0 = ldnt4(Wb);
    b1 = ldnt4(Wb + HD);
  }
  a0 = *(const short8*)(agA[0]);
  a1 = *(const short8*)(agA[1]);
  a2 = *(const short8*)(agA[2]);
  a3 = *(const short8*)(agA[3]);
  if (tid < 128) BT_TRANSPOSE_STORE(Blds[0] + bofs)
  __syncthreads();

  for (int ks = 0; ks < 32; ++ks) {
    const int cur = ks & 1, nxt = cur ^ 1;
    const bool more = (ks + 1) < 32;
    if (more) {
      if (tid < 128) {
        const float* bp = Wb + (size_t)(ks + 1) * 32 * HD;
        b0 = ldnt4(bp);
        b1 = ldnt4(bp + HD);
      }
      a0n = *(const short8*)(agA[0] + (ks + 1) * 32);
      a1n = *(const short8*)(agA[1] + (ks + 1) * 32);
      a2n = *(const short8*)(agA[2] + (ks + 1) * 32);
      a3n = *(const short8*)(agA[3] + (ks + 1) * 32);
    }
    short8 bfr[2];
#pragma unroll
    for (int ni = 0; ni < 2; ++ni)
      bfr[ni] = *(const short8*)(Blds[cur] + (ni * 16 + fr) * 16 + q * 4);
#pragma unroll
    for (int ni = 0; ni < 2; ++ni) {
      acc[0][ni] = __builtin_amdgcn_mfma_f32_16x16x32_bf16(a0, bfr[ni], acc[0][ni], 0, 0, 0);
      acc[1][ni] = __builtin_amdgcn_mfma_f32_16x16x32_bf16(a1, bfr[ni], acc[1][ni], 0, 0, 0);
      acc[2][ni] = __builtin_amdgcn_mfma_f32_16x16x32_bf16(a2, bfr[ni], acc[2][ni], 0, 0, 0);
      acc[3][ni] = __builtin_amdgcn_mfma_f32_16x16x32_bf16(a3, bfr[ni], acc[3][ni], 0, 0, 0);
    }
    if (more && tid < 128) BT_TRANSPOSE_STORE(Blds[nxt] + bofs)
    __syncthreads();
    a0 = a0n; a1 = a1n; a2 = a2n; a3 = a3n;
  }

  // epilogue: weighted atomic accumulation into out (bd already pre-mixed by router)
#pragma unroll
  for (int mi = 0; mi < 4; ++mi) {
#pragma unroll
    for (int r = 0; r < 4; ++r) {
      const int srow = wv * 64 + mi * 16 + q * 4 + r;
      if ((mtile * 256 + srow) < Ne) {
        const int gsl = base + srow;
        const int tok = gtok[gsl];
        const float wt = gwt[gsl];
        float* op = out + (size_t)tok * HD + ntile * 32;
#pragma unroll
        for (int ni = 0; ni < 2; ++ni) {
          const int col = ni * 16 + fr;
          atomicAdd(op + col, wt * acc[mi][ni][r]);
        }
      }
    }
  }
}

extern "C" void kernel_launch(void* const* d_in, const int* in_sizes, int n_in,
                              void* d_out, int out_size, void* d_ws, size_t ws_size,
                              hipStream_t stream) {
  const float* x   = (const float*)d_in[0];
  const float* Wg  = (const float*)d_in[1];
  const float* bg  = (const float*)d_in[2];
  const float* Wgu = (const float*)d_in[3];
  const float* bgu = (const float*)d_in[4];
  const float* Wd  = (const float*)d_in[5];
  const float* bd  = (const float*)d_in[6];
  float* out = (float*)d_out;

  int* cnt = (int*)d_ws;                    // 16
  int* off = cnt + 16;                      // 16
  int* e01 = off + 16;                      // 1024
  float* w0f = (float*)(e01 + NT);          // 1024
  float* w1f = w0f + NT;                    // 1024
  int* gtok = (int*)(w1f + NT);             // GROWS
  float* gwt = (float*)(gtok + GROWS);      // GROWS
  unsigned short* Xbf = (unsigned short*)(gwt + GROWS);        // NT*HD bf16
  unsigned short* Gact = Xbf + (size_t)NT * HD;                // GROWS*ED bf16

  k_router<<<NT, 256, 0, stream>>>(x, Wg, bg, bd, e01, w0f, w1f, Xbf, out);
  k_scan<<<1, NT, 0, stream>>>(e01, w0f, w1f, cnt, off, gtok, gwt);
  k_gemm1<<<dim3(32, 2, NEXPERT), 256, 0, stream>>>(Xbf, Wgu, bgu, cnt, off, gtok, Gact);
  k_gemm2<<<dim3(32, 2, NEXPERT), 256, 0, stream>>>(Gact, Wd, cnt, off, gtok, gwt, out);
}

// Round 7
// 339.052 us; speedup vs baseline: 1.1100x; 1.1100x over previous
//
#include <hip/hip_runtime.h>
#include <hip/hip_bf16.h>

#define NT 1024     // tokens (B*S)
#define HD 1024     // hidden
#define ED 1024     // expert inner dim
#define F2D 2048    // 2*E (interleaved gate/up)
#define NEXPERT 16
#define GROWS 2304  // compacted rows (2048) + tile slack (gemm reads up to base+255 <= 2303)
#define ALPHA_C 1.702f
#define LIMIT_C 7.0f

typedef float f32x4 __attribute__((ext_vector_type(4)));
typedef float fv4 __attribute__((ext_vector_type(4)));
typedef short short8 __attribute__((ext_vector_type(8)));
typedef unsigned int u32x4 __attribute__((ext_vector_type(4)));

__device__ __forceinline__ unsigned short f2bf(float x) {
  union { float f; unsigned int u; } v; v.f = x;
  unsigned int r = v.u + 0x7FFFu + ((v.u >> 16) & 1u);
  return (unsigned short)(r >> 16);
}
__device__ __forceinline__ unsigned int pk2(float lo, float hi) {
  return (unsigned int)f2bf(lo) | ((unsigned int)f2bf(hi) << 16);
}
// non-temporal float4 load (weights: stream, don't cache)
__device__ __forceinline__ fv4 ldnt4(const float* p) {
  return __builtin_nontemporal_load((const fv4*)p);
}
// async global->LDS, 16B per lane; LDS dest = wave-uniform base + lane*16
__device__ __forceinline__ void async16(const void* g, void* l) {
  __builtin_amdgcn_global_load_lds((const __attribute__((address_space(1))) void*)g,
                                   (__attribute__((address_space(3))) void*)l, 16, 0, 0);
}

// in-quad 4x4 transpose (XOR network via DPP quad_perm) + b128 LDS store.
// requires: b0,b1 (fv4 weight rows k=2*kpair, 2*kpair+1), sub = lane&3 in scope.
// verified correct in rounds 4/5/6 (passing absmax).
#define BT_TRANSPOSE_STORE(DST)                                                         \
  {                                                                                     \
    unsigned int w0p = pk2(b0[0], b1[0]);                                               \
    unsigned int w1p = pk2(b0[1], b1[1]);                                               \
    unsigned int w2p = pk2(b0[2], b1[2]);                                               \
    unsigned int w3p = pk2(b0[3], b1[3]);                                               \
    unsigned int X0 = sub == 0 ? w0p : sub == 1 ? w1p : sub == 2 ? w2p : w3p;           \
    unsigned int X1 = sub == 0 ? w1p : sub == 1 ? w0p : sub == 2 ? w3p : w2p;           \
    unsigned int X2 = sub == 0 ? w2p : sub == 1 ? w3p : sub == 2 ? w0p : w1p;           \
    unsigned int X3 = sub == 0 ? w3p : sub == 1 ? w2p : sub == 2 ? w1p : w0p;           \
    unsigned int r0 = X0;                                                               \
    unsigned int r1 = (unsigned int)__builtin_amdgcn_update_dpp((int)X1, (int)X1, 0xB1, 0xF, 0xF, 0); \
    unsigned int r2 = (unsigned int)__builtin_amdgcn_update_dpp((int)X2, (int)X2, 0x4E, 0xF, 0xF, 0); \
    unsigned int r3 = (unsigned int)__builtin_amdgcn_update_dpp((int)X3, (int)X3, 0x1B, 0xF, 0xF, 0); \
    u32x4 tt;                                                                           \
    tt[0] = sub == 0 ? r0 : sub == 1 ? r1 : sub == 2 ? r2 : r3;                         \
    tt[1] = sub == 0 ? r1 : sub == 1 ? r0 : sub == 2 ? r3 : r2;                         \
    tt[2] = sub == 0 ? r2 : sub == 1 ? r3 : sub == 2 ? r0 : r1;                         \
    tt[3] = sub == 0 ? r3 : sub == 1 ? r2 : sub == 2 ? r1 : r0;                         \
    *(u32x4*)(DST) = tt;                                                                \
  }

// ---------------- router: 4 waves/token; partial logits per wave, LDS reduce, redundant top-2 ----------------
__global__ __launch_bounds__(256) void k_router(const float* __restrict__ x,
                                                const float* __restrict__ Wg,
                                                const float* __restrict__ bg,
                                                const float* __restrict__ bd,
                                                int* __restrict__ e01,
                                                float* __restrict__ w0f,
                                                float* __restrict__ w1f,
                                                unsigned short* __restrict__ Xbf,
                                                float* __restrict__ out) {
  const int t = blockIdx.x;
  const int tid = threadIdx.x;     // 0..255
  const int w = tid >> 6;          // wave 0..3 (quarter of HD)
  const int l = tid & 63;
  const float4* x4 = (const float4*)(x + (size_t)t * HD);
  // bf16 conversion: one float4 per thread
  {
    float4 v = x4[tid];
    unsigned int* dst = (unsigned int*)(Xbf + (size_t)t * HD + tid * 4);
    dst[0] = pk2(v.x, v.y); dst[1] = pk2(v.z, v.w);
  }
  // partial logits: expert e = l&15, sub-chunk qq = l>>4; wave w covers float4 idx w*64..w*64+63
  const int e = l & 15, qq = l >> 4;
  const float4* wg4 = (const float4*)(Wg + (size_t)e * HD);
  float s = 0.f;
#pragma unroll 4
  for (int j = 0; j < 16; ++j) {
    const int idx = w * 64 + qq + 4 * j;
    float4 a = x4[idx], b = wg4[idx];
    s += a.x * b.x + a.y * b.y + a.z * b.z + a.w * b.w;
  }
  s += __shfl_xor(s, 16);
  s += __shfl_xor(s, 32);          // lanes 0..15 hold quarter-partial for expert e
  __shared__ float slog[4][16];
  if (l < 16) slog[w][e] = s;
  __syncthreads();
  // all threads: full logits + top2 (redundant, deterministic)
  float v0 = -1e30f, v1 = -1e30f; int i0 = 0, i1 = 0;
  for (int k2 = 0; k2 < 16; ++k2) {
    float lv = slog[0][k2] + slog[1][k2] + slog[2][k2] + slog[3][k2] + bg[k2];
    if (lv > v0) { v1 = v0; i1 = i0; v0 = lv; i0 = k2; }
    else if (lv > v1) { v1 = lv; i1 = k2; }
  }
  const float w0 = 1.f / (1.f + __expf(v1 - v0));
  const float w1 = 1.f - w0;
  if (tid == 0) {
    e01[t] = i0 | (i1 << 8);
    w0f[t] = w0;
    w1f[t] = w1;
  }
  // bd premix: one float4 per thread
  const float4* bd0 = (const float4*)(bd + (size_t)i0 * HD);
  const float4* bd1 = (const float4*)(bd + (size_t)i1 * HD);
  float4 a = bd0[tid], b = bd1[tid];
  float4 r;
  r.x = w0 * a.x + w1 * b.x;
  r.y = w0 * a.y + w1 * b.y;
  r.z = w0 * a.z + w1 * b.z;
  r.w = w0 * a.w + w1 * b.w;
  ((float4*)(out + (size_t)t * HD))[tid] = r;
}

// ---------------- scan: counts, offsets, placement (one block) ----------------
__global__ __launch_bounds__(1024) void k_scan(const int* __restrict__ e01,
                                               const float* __restrict__ w0f,
                                               const float* __restrict__ w1f,
                                               int* __restrict__ cnt,
                                               int* __restrict__ off,
                                               int* __restrict__ gtok,
                                               float* __restrict__ gwt) {
  __shared__ int scnt[NEXPERT];
  __shared__ int soff[NEXPERT];
  __shared__ int scur[NEXPERT];
  const int t = threadIdx.x;
  if (t < NEXPERT) { scnt[t] = 0; scur[t] = 0; }
  __syncthreads();
  const int p = e01[t];
  const int e0 = p & 255, e1 = p >> 8;
  atomicAdd(&scnt[e0], 1);
  atomicAdd(&scnt[e1], 1);
  __syncthreads();
  if (t == 0) {
    int a = 0;
    for (int e = 0; e < NEXPERT; ++e) { soff[e] = a; off[e] = a; cnt[e] = scnt[e]; a += scnt[e]; }
  }
  __syncthreads();
  int s0 = atomicAdd(&scur[e0], 1);
  gtok[soff[e0] + s0] = t; gwt[soff[e0] + s0] = w0f[t];
  int s1 = atomicAdd(&scur[e1], 1);
  gtok[soff[e1] + s1] = t; gwt[soff[e1] + s1] = w1f[t];
}

// ---------------- GEMM1: block 256M x 64N, 256 thr (4 waves x 64 rows), BK=32, dbuf ----------------
// grid (32 ntiles, 2 mtiles, 16 experts) -> ~512 working blocks = 2/CU (round-6 occupancy win kept).
// NEW: XOR chunk-swizzle (rule 21) on A and B to kill the 8-way LDS bank conflicts measured in r5/r6:
//   A: global source chunk = c ^ ((row>>1)&3), LDS linear (async16-compatible); read chunk xq = q ^ ((fr>>1)&3).
//   B: ds_write kblock slot = kb ^ ((col>>1)&3); read uses same xq.
__global__ __launch_bounds__(256) void k_gemm1(const unsigned short* __restrict__ Xbf,
                                               const float* __restrict__ Wgu,
                                               const float* __restrict__ bgu,
                                               const int* __restrict__ cnt,
                                               const int* __restrict__ off,
                                               const int* __restrict__ gtok,
                                               unsigned short* __restrict__ Gact) {
  const int e = blockIdx.z;
  const int Ne = cnt[e];
  const int mtile = blockIdx.y;
  if (mtile * 256 >= Ne) return;
  const int ntile = blockIdx.x;         // 0..31, 64 cols each
  const int tid = threadIdx.x;          // 0..255
  const int lane = tid & 63;
  const int wv = tid >> 6;              // 0..3 (M 64-slice)
  const int q = lane >> 4;
  const int fr = lane & 15;
  const int xq = q ^ ((fr >> 1) & 3);   // swizzled chunk/kblock index for LDS reads
  const int base = off[e] + mtile * 256;

  __shared__ unsigned short Alds[2][256 * 32];   // [buf][row*32 + k]  32 KB (linear for async16)
  __shared__ unsigned int Blds[2][64 * 16];      // transposed [col][kblock-swz] 8 KB

  // A staging: thread stages rows (tid>>2) + j*64 (j=0..3); global chunk = (tid&3) ^ ((arow>>1)&3)
  const int arow = tid >> 2;
  const int cs = (tid & 3) ^ ((arow >> 1) & 3);   // (row>>1)&3 is j-invariant (64/2 = 32 ≡ 0 mod 4)
  const unsigned short* agp[4];
#pragma unroll
  for (int j = 0; j < 4; ++j) {
    const int r = arow + j * 64;
    const int ags = base + (((mtile * 256 + r) < Ne) ? r : 0);
    agp[j] = Xbf + (size_t)gtok[ags] * HD + cs * 8;
  }
  const int aofs = tid * 8;   // shorts; + j*2048

  // B staging: sub = tid&3, quad = tid>>2: colgrp = quad&15 (0..15), kblock = quad>>4 (0..3)
  // thread loads kpair kblock*4+sub, cols colgrp*4..+3; post-transpose writes col colgrp*4+sub,
  // at swizzled kblock slot kb' = kblock ^ ((col>>1)&3).
  const int sub = tid & 3;
  const int quad = tid >> 2;
  const int colgrp = quad & 15;
  const int kblock = quad >> 4;
  const float* Wb = Wgu + (size_t)e * HD * F2D + (size_t)(2 * (kblock * 4 + sub)) * F2D + ntile * 64 + colgrp * 4;
  const int bcol = colgrp * 4 + sub;
  const int bofs = bcol * 16 + (kblock ^ ((bcol >> 1) & 3)) * 4;   // dword offset of b128 store

  f32x4 acc[4][4] = {};
  fv4 b0, b1;

  // prologue: stage tile 0
  b0 = ldnt4(Wb);
  b1 = ldnt4(Wb + F2D);
#pragma unroll
  for (int j = 0; j < 4; ++j)
    async16(agp[j], Alds[0] + aofs + j * 2048);
  BT_TRANSPOSE_STORE(Blds[0] + bofs)
  __syncthreads();

  for (int ks = 0; ks < 32; ++ks) {
    const int cur = ks & 1, nxt = cur ^ 1;
    const bool more = (ks + 1) < 32;
    if (more) {
      const float* bp = Wb + (size_t)(ks + 1) * 32 * F2D;
      b0 = ldnt4(bp);
      b1 = ldnt4(bp + F2D);
#pragma unroll
      for (int j = 0; j < 4; ++j)
        async16(agp[j] + (ks + 1) * 32, Alds[nxt] + aofs + j * 2048);
    }
    short8 af[4], bfr[4];
#pragma unroll
    for (int mi = 0; mi < 4; ++mi)
      af[mi] = *(const short8*)(Alds[cur] + (wv * 64 + mi * 16 + fr) * 32 + xq * 8);
#pragma unroll
    for (int ni = 0; ni < 4; ++ni)
      bfr[ni] = *(const short8*)(Blds[cur] + (ni * 16 + fr) * 16 + xq * 4);
#pragma unroll
    for (int mi = 0; mi < 4; ++mi)
#pragma unroll
      for (int ni = 0; ni < 4; ++ni)
        acc[mi][ni] = __builtin_amdgcn_mfma_f32_16x16x32_bf16(af[mi], bfr[ni], acc[mi][ni], 0, 0, 0);
    if (more) BT_TRANSPOSE_STORE(Blds[nxt] + bofs)
    __syncthreads();
  }

  // epilogue: +bgu, de-interleave gate/up via lane-pair shuffle, activation, store bf16
  const float* bguE = bgu + (size_t)e * F2D + ntile * 64;
#pragma unroll
  for (int mi = 0; mi < 4; ++mi) {
#pragma unroll
    for (int ni = 0; ni < 4; ++ni) {
      const int coll = ni * 16 + fr;
      const float bias = bguE[coll];
#pragma unroll
      for (int r = 0; r < 4; ++r) {
        const int srow = wv * 64 + mi * 16 + q * 4 + r;
        float v = acc[mi][ni][r] + bias;
        float pv = __shfl_xor(v, 1);
        float gate = (lane & 1) ? pv : v;   // even f2-cols are gate, odd are up
        float up   = (lane & 1) ? v : pv;
        gate = fminf(gate, LIMIT_C);
        up = fminf(fmaxf(up, -LIMIT_C), LIMIT_C);
        float glu = gate / (1.f + __expf(-ALPHA_C * gate));
        float val = (up + 1.f) * glu;
        if (!(lane & 1) && (mtile * 256 + srow) < Ne)
          Gact[(size_t)(base + srow) * ED + ((ntile * 64 + coll) >> 1)] = f2bf(val);
      }
    }
  }
}

// ---------------- GEMM2: round-4 proven config (verbatim): block 256M x 64N, 512 thr, BK=32, dbuf ----------------
// A staged via async16 (LDS), B DPP-transposed [col][kpair] stride 20 dwords. Atomic epilogue.
// grid (16 ntiles, 2 mtiles, 16 experts).
#define BSTG2T 20
__global__ __launch_bounds__(512, 2) void k_gemm2(const unsigned short* __restrict__ Gact,
                                                  const float* __restrict__ Wd,
                                                  const int* __restrict__ cnt,
                                                  const int* __restrict__ off,
                                                  const int* __restrict__ gtok,
                                                  const float* __restrict__ gwt,
                                                  float* __restrict__ out) {
  const int e = blockIdx.z;
  const int Ne = cnt[e];
  const int mtile = blockIdx.y;
  if (mtile * 256 >= Ne) return;
  const int ntile = blockIdx.x;
  const int tid = threadIdx.x;          // 0..511
  const int lane = tid & 63;
  const int wv = tid >> 6;              // 0..7 (M 32-slice; N full 64)
  const int q = lane >> 4;
  const int fr = lane & 15;
  const int base = off[e] + mtile * 256;

  __shared__ unsigned short Alds[2][256 * 32];     // 32 KB
  __shared__ unsigned int Blds[2][64 * BSTG2T];    // transposed B, ~10.2 KB

  // A staging: wave wv stages rows wv*32 + (lane>>2) and +16; chunk = lane&3
  // rows base+0..255 < GROWS: safe
  const int ar0 = wv * 32 + (lane >> 2);
  const unsigned short* agp0 = Gact + (size_t)(base + ar0) * ED + (lane & 3) * 8;
  const unsigned short* agp1 = agp0 + (size_t)16 * ED;
  const int aofs = wv * 1024;  // shorts: 32 rows * 32 shorts

  // B staging (waves 0..3): sub = lane&3; kpair = wv*4+sub; cols (lane>>2)*4..+3;
  // post-transpose lane writes col = lane, kpairs wv*4..+3.
  const int sub = lane & 3;
  const float* Wb = Wd + (size_t)e * ED * HD + (size_t)(2 * (wv * 4 + sub)) * HD + ntile * 64 + (lane >> 2) * 4;
  const int bofs = lane * BSTG2T + wv * 4;

  f32x4 acc[2][4] = {};
  fv4 b0, b1;

  if (tid < 256) {
    b0 = ldnt4(Wb);
    b1 = ldnt4(Wb + HD);
  }
  async16(agp0, Alds[0] + aofs);
  async16(agp1, Alds[0] + aofs + 512);
  if (tid < 256) BT_TRANSPOSE_STORE(Blds[0] + bofs)
  __syncthreads();

  for (int ks = 0; ks < 32; ++ks) {
    const int cur = ks & 1, nxt = cur ^ 1;
    const bool more = (ks + 1) < 32;
    if (more) {
      if (tid < 256) {
        const float* bp = Wb + (size_t)(ks + 1) * 32 * HD;
        b0 = ldnt4(bp);
        b1 = ldnt4(bp + HD);
      }
      async16(agp0 + (ks + 1) * 32, Alds[nxt] + aofs);
      async16(agp1 + (ks + 1) * 32, Alds[nxt] + aofs + 512);
    }
    short8 af[2], bfr[4];
#pragma unroll
    for (int mi = 0; mi < 2; ++mi)
      af[mi] = *(const short8*)(Alds[cur] + (wv * 32 + mi * 16 + fr) * 32 + q * 8);
#pragma unroll
    for (int ni = 0; ni < 4; ++ni)
      bfr[ni] = *(const short8*)(Blds[cur] + (ni * 16 + fr) * BSTG2T + q * 4);
#pragma unroll
    for (int mi = 0; mi < 2; ++mi)
#pragma unroll
      for (int ni = 0; ni < 4; ++ni)
        acc[mi][ni] = __builtin_amdgcn_mfma_f32_16x16x32_bf16(af[mi], bfr[ni], acc[mi][ni], 0, 0, 0);
    if (more && tid < 256) BT_TRANSPOSE_STORE(Blds[nxt] + bofs)
    __syncthreads();
  }

  // epilogue: weighted atomic accumulation into out (bd already pre-mixed by router)
#pragma unroll
  for (int mi = 0; mi < 2; ++mi) {
#pragma unroll
    for (int r = 0; r < 4; ++r) {
      const int srow = wv * 32 + mi * 16 + q * 4 + r;
      if ((mtile * 256 + srow) < Ne) {
        const int gsl = base + srow;
        const int tok = gtok[gsl];
        const float wt = gwt[gsl];
        float* op = out + (size_t)tok * HD + ntile * 64;
#pragma unroll
        for (int ni = 0; ni < 4; ++ni) {
          const int col = ni * 16 + fr;
          atomicAdd(op + col, wt * acc[mi][ni][r]);
        }
      }
    }
  }
}

extern "C" void kernel_launch(void* const* d_in, const int* in_sizes, int n_in,
                              void* d_out, int out_size, void* d_ws, size_t ws_size,
                              hipStream_t stream) {
  const float* x   = (const float*)d_in[0];
  const float* Wg  = (const float*)d_in[1];
  const float* bg  = (const float*)d_in[2];
  const float* Wgu = (const float*)d_in[3];
  const float* bgu = (const float*)d_in[4];
  const float* Wd  = (const float*)d_in[5];
  const float* bd  = (const float*)d_in[6];
  float* out = (float*)d_out;

  int* cnt = (int*)d_ws;                    // 16
  int* off = cnt + 16;                      // 16
  int* e01 = off + 16;                      // 1024
  float* w0f = (float*)(e01 + NT);          // 1024
  float* w1f = w0f + NT;                    // 1024
  int* gtok = (int*)(w1f + NT);             // GROWS
  float* gwt = (float*)(gtok + GROWS);      // GROWS
  unsigned short* Xbf = (unsigned short*)(gwt + GROWS);        // NT*HD bf16
  unsigned short* Gact = Xbf + (size_t)NT * HD;                // GROWS*ED bf16

  k_router<<<NT, 256, 0, stream>>>(x, Wg, bg, bd, e01, w0f, w1f, Xbf, out);
  k_scan<<<1, NT, 0, stream>>>(e01, w0f, w1f, cnt, off, gtok, gwt);
  k_gemm1<<<dim3(32, 2, NEXPERT), 256, 0, stream>>>(Xbf, Wgu, bgu, cnt, off, gtok, Gact);
  k_gemm2<<<dim3(16, 2, NEXPERT), 512, 0, stream>>>(Gact, Wd, cnt, off, gtok, gwt, out);
}

// Round 8
// 323.677 us; speedup vs baseline: 1.1627x; 1.0475x over previous
//
#include <hip/hip_runtime.h>
#include <hip/hip_bf16.h>

#define NT 1024     // tokens (B*S)
#define HD 1024     // hidden
#define ED 1024     // expert inner dim
#define F2D 2048    // 2*E (interleaved gate/up)
#define NEXPERT 16
#define GROWS 2304  // compacted rows (2048) + tile slack (gemm reads up to base+255 <= 2303)
#define ALPHA_C 1.702f
#define LIMIT_C 7.0f

typedef float f32x4 __attribute__((ext_vector_type(4)));
typedef float fv4 __attribute__((ext_vector_type(4)));
typedef short short8 __attribute__((ext_vector_type(8)));
typedef unsigned int u32x4 __attribute__((ext_vector_type(4)));

__device__ __forceinline__ unsigned short f2bf(float x) {
  union { float f; unsigned int u; } v; v.f = x;
  unsigned int r = v.u + 0x7FFFu + ((v.u >> 16) & 1u);
  return (unsigned short)(r >> 16);
}
__device__ __forceinline__ unsigned int pk2(float lo, float hi) {
  return (unsigned int)f2bf(lo) | ((unsigned int)f2bf(hi) << 16);
}
// non-temporal float4 load (weights: stream, don't cache)
__device__ __forceinline__ fv4 ldnt4(const float* p) {
  return __builtin_nontemporal_load((const fv4*)p);
}
// async global->LDS, 16B per lane; LDS dest = wave-uniform base + lane*16
__device__ __forceinline__ void async16(const void* g, void* l) {
  __builtin_amdgcn_global_load_lds((const __attribute__((address_space(1))) void*)g,
                                   (__attribute__((address_space(3))) void*)l, 16, 0, 0);
}

// in-quad 4x4 transpose (XOR network via DPP quad_perm) + b128 LDS store.
// requires: b0,b1 (fv4 weight rows k=2*kpair, 2*kpair+1), sub = lane&3 in scope.
// verified correct in rounds 4-7 (passing absmax).
#define BT_TRANSPOSE_STORE(DST)                                                         \
  {                                                                                     \
    unsigned int w0p = pk2(b0[0], b1[0]);                                               \
    unsigned int w1p = pk2(b0[1], b1[1]);                                               \
    unsigned int w2p = pk2(b0[2], b1[2]);                                               \
    unsigned int w3p = pk2(b0[3], b1[3]);                                               \
    unsigned int X0 = sub == 0 ? w0p : sub == 1 ? w1p : sub == 2 ? w2p : w3p;           \
    unsigned int X1 = sub == 0 ? w1p : sub == 1 ? w0p : sub == 2 ? w3p : w2p;           \
    unsigned int X2 = sub == 0 ? w2p : sub == 1 ? w3p : sub == 2 ? w0p : w1p;           \
    unsigned int X3 = sub == 0 ? w3p : sub == 1 ? w2p : sub == 2 ? w1p : w0p;           \
    unsigned int r0 = X0;                                                               \
    unsigned int r1 = (unsigned int)__builtin_amdgcn_update_dpp((int)X1, (int)X1, 0xB1, 0xF, 0xF, 0); \
    unsigned int r2 = (unsigned int)__builtin_amdgcn_update_dpp((int)X2, (int)X2, 0x4E, 0xF, 0xF, 0); \
    unsigned int r3 = (unsigned int)__builtin_amdgcn_update_dpp((int)X3, (int)X3, 0x1B, 0xF, 0xF, 0); \
    u32x4 tt;                                                                           \
    tt[0] = sub == 0 ? r0 : sub == 1 ? r1 : sub == 2 ? r2 : r3;                         \
    tt[1] = sub == 0 ? r1 : sub == 1 ? r0 : sub == 2 ? r3 : r2;                         \
    tt[2] = sub == 0 ? r2 : sub == 1 ? r3 : sub == 2 ? r0 : r1;                         \
    tt[3] = sub == 0 ? r3 : sub == 1 ? r2 : sub == 2 ? r1 : r0;                         \
    *(u32x4*)(DST) = tt;                                                                \
  }

// ---------------- router: 4 waves/token; partial logits per wave, LDS reduce, redundant top-2 ----------------
__global__ __launch_bounds__(256) void k_router(const float* __restrict__ x,
                                                const float* __restrict__ Wg,
                                                const float* __restrict__ bg,
                                                const float* __restrict__ bd,
                                                int* __restrict__ e01,
                                                float* __restrict__ w0f,
                                                float* __restrict__ w1f,
                                                unsigned short* __restrict__ Xbf,
                                                float* __restrict__ out) {
  const int t = blockIdx.x;
  const int tid = threadIdx.x;     // 0..255
  const int w = tid >> 6;          // wave 0..3 (quarter of HD)
  const int l = tid & 63;
  const float4* x4 = (const float4*)(x + (size_t)t * HD);
  // bf16 conversion: one float4 per thread
  {
    float4 v = x4[tid];
    unsigned int* dst = (unsigned int*)(Xbf + (size_t)t * HD + tid * 4);
    dst[0] = pk2(v.x, v.y); dst[1] = pk2(v.z, v.w);
  }
  // partial logits: expert e = l&15, sub-chunk qq = l>>4; wave w covers float4 idx w*64..w*64+63
  const int e = l & 15, qq = l >> 4;
  const float4* wg4 = (const float4*)(Wg + (size_t)e * HD);
  float s = 0.f;
#pragma unroll 4
  for (int j = 0; j < 16; ++j) {
    const int idx = w * 64 + qq + 4 * j;
    float4 a = x4[idx], b = wg4[idx];
    s += a.x * b.x + a.y * b.y + a.z * b.z + a.w * b.w;
  }
  s += __shfl_xor(s, 16);
  s += __shfl_xor(s, 32);          // lanes 0..15 hold quarter-partial for expert e
  __shared__ float slog[4][16];
  if (l < 16) slog[w][e] = s;
  __syncthreads();
  // all threads: full logits + top2 (redundant, deterministic)
  float v0 = -1e30f, v1 = -1e30f; int i0 = 0, i1 = 0;
  for (int k2 = 0; k2 < 16; ++k2) {
    float lv = slog[0][k2] + slog[1][k2] + slog[2][k2] + slog[3][k2] + bg[k2];
    if (lv > v0) { v1 = v0; i1 = i0; v0 = lv; i0 = k2; }
    else if (lv > v1) { v1 = lv; i1 = k2; }
  }
  const float w0 = 1.f / (1.f + __expf(v1 - v0));
  const float w1 = 1.f - w0;
  if (tid == 0) {
    e01[t] = i0 | (i1 << 8);
    w0f[t] = w0;
    w1f[t] = w1;
  }
  // bd premix: one float4 per thread
  const float4* bd0 = (const float4*)(bd + (size_t)i0 * HD);
  const float4* bd1 = (const float4*)(bd + (size_t)i1 * HD);
  float4 a = bd0[tid], b = bd1[tid];
  float4 r;
  r.x = w0 * a.x + w1 * b.x;
  r.y = w0 * a.y + w1 * b.y;
  r.z = w0 * a.z + w1 * b.z;
  r.w = w0 * a.w + w1 * b.w;
  ((float4*)(out + (size_t)t * HD))[tid] = r;
}

// ---------------- scan: counts, offsets, placement (one block) ----------------
__global__ __launch_bounds__(1024) void k_scan(const int* __restrict__ e01,
                                               const float* __restrict__ w0f,
                                               const float* __restrict__ w1f,
                                               int* __restrict__ cnt,
                                               int* __restrict__ off,
                                               int* __restrict__ gtok,
                                               float* __restrict__ gwt) {
  __shared__ int scnt[NEXPERT];
  __shared__ int soff[NEXPERT];
  __shared__ int scur[NEXPERT];
  const int t = threadIdx.x;
  if (t < NEXPERT) { scnt[t] = 0; scur[t] = 0; }
  __syncthreads();
  const int p = e01[t];
  const int e0 = p & 255, e1 = p >> 8;
  atomicAdd(&scnt[e0], 1);
  atomicAdd(&scnt[e1], 1);
  __syncthreads();
  if (t == 0) {
    int a = 0;
    for (int e = 0; e < NEXPERT; ++e) { soff[e] = a; off[e] = a; cnt[e] = scnt[e]; a += scnt[e]; }
  }
  __syncthreads();
  int s0 = atomicAdd(&scur[e0], 1);
  gtok[soff[e0] + s0] = t; gwt[soff[e0] + s0] = w0f[t];
  int s1 = atomicAdd(&scur[e1], 1);
  gtok[soff[e1] + s1] = t; gwt[soff[e1] + s1] = w1f[t];
}

// ---------------- GEMM1: 256M x 64N, 256 thr (4 waves x 64 rows), BK=32 ----------------
// COUNTED-VMCNT PIPELINE (T3/T4): 3-buffer LDS, 2-deep prefetch, raw s_barrier, vmcnt never
// drained to 0 in steady state. Ping-pong B-regs (static parity). r7 swizzles kept (0 conflicts).
// Steady state: 12 vmem ops outstanding/thread; wait vmcnt(6) -> tile ks+1 landed, ks+2 in flight.
__global__ __launch_bounds__(256) void k_gemm1(const unsigned short* __restrict__ Xbf,
                                               const float* __restrict__ Wgu,
                                               const float* __restrict__ bgu,
                                               const int* __restrict__ cnt,
                                               const int* __restrict__ off,
                                               const int* __restrict__ gtok,
                                               unsigned short* __restrict__ Gact) {
  const int e = blockIdx.z;
  const int Ne = cnt[e];
  const int mtile = blockIdx.y;
  if (mtile * 256 >= Ne) return;
  const int ntile = blockIdx.x;         // 0..31, 64 cols each
  const int tid = threadIdx.x;          // 0..255
  const int lane = tid & 63;
  const int wv = tid >> 6;              // 0..3 (M 64-slice)
  const int q = lane >> 4;
  const int fr = lane & 15;
  const int xq = q ^ ((fr >> 1) & 3);   // swizzled chunk/kblock index for LDS reads
  const int base = off[e] + mtile * 256;

  __shared__ unsigned short AldsL[3 * 8192];   // 3 x 256 rows x 32 shorts = 48 KB (linear, async16)
  __shared__ unsigned int BldsL[3 * 1024];     // 3 x 64 cols x 16 dwords (transposed) = 12 KB

  // A staging: thread stages rows (tid>>2) + j*64 (j=0..3); global chunk = (tid&3) ^ ((arow>>1)&3)
  const int arow = tid >> 2;
  const int cs = (tid & 3) ^ ((arow >> 1) & 3);
  const unsigned short* agp[4];
#pragma unroll
  for (int j = 0; j < 4; ++j) {
    const int r = arow + j * 64;
    const int ags = base + (((mtile * 256 + r) < Ne) ? r : 0);
    agp[j] = Xbf + (size_t)gtok[ags] * HD + cs * 8;
  }
  const int aofs = tid * 8;   // shorts; + j*2048

  // B staging: sub = tid&3, quad = tid>>2: colgrp = quad&15, kblock = quad>>4
  const int sub = tid & 3;
  const int quad = tid >> 2;
  const int colgrp = quad & 15;
  const int kblock = quad >> 4;
  const float* Wb = Wgu + (size_t)e * HD * F2D + (size_t)(2 * (kblock * 4 + sub)) * F2D + ntile * 64 + colgrp * 4;
  const int bcol = colgrp * 4 + sub;
  const int bofs = bcol * 16 + (kblock ^ ((bcol >> 1) & 3)) * 4;   // swizzled b128 store slot

  f32x4 acc[4][4] = {};
  fv4 b0A, b1A, b0B, b1B;   // ping-pong: tile loaded at even ks -> A-regs, odd ks -> B-regs

  // ---- prologue: issue tiles 0 and 1; store B0; one barrier ----
  b0A = ldnt4(Wb);                       // tile0 B
  b1A = ldnt4(Wb + F2D);
#pragma unroll
  for (int j = 0; j < 4; ++j)
    async16(agp[j], AldsL + aofs + j * 2048);                 // tile0 A -> buf0
  b0B = ldnt4(Wb + (size_t)32 * F2D);    // tile1 B
  b1B = ldnt4(Wb + (size_t)33 * F2D);
#pragma unroll
  for (int j = 0; j < 4; ++j)
    async16(agp[j] + 32, AldsL + 8192 + aofs + j * 2048);     // tile1 A -> buf1
  asm volatile("s_waitcnt vmcnt(6)" ::: "memory");            // tile0's 6 done; tile1's in flight
  __builtin_amdgcn_sched_barrier(0);
  { fv4 b0 = b0A, b1 = b1A; BT_TRANSPOSE_STORE(BldsL + bofs) }  // store B0 -> buf0
  asm volatile("s_waitcnt lgkmcnt(0)" ::: "memory");
  __builtin_amdgcn_s_barrier();
  __builtin_amdgcn_sched_barrier(0);

  int cur = 0, nx1 = 1, nx2 = 2;
  for (int ks = 0; ks < 32; ++ks) {
    // 1) ds_read current tile fragments
    short8 af[4], bfr[4];
    const unsigned short* Ab = AldsL + cur * 8192;
    const unsigned int* Bb = BldsL + cur * 1024;
#pragma unroll
    for (int mi = 0; mi < 4; ++mi)
      af[mi] = *(const short8*)(Ab + (wv * 64 + mi * 16 + fr) * 32 + xq * 8);
#pragma unroll
    for (int ni = 0; ni < 4; ++ni)
      bfr[ni] = *(const short8*)(Bb + (ni * 16 + fr) * 16 + xq * 4);
    // 2) issue tile ks+2 loads (B -> regs[ks&1], A -> LDS buf nx2)
    if (ks < 30) {
      const float* bp = Wb + (size_t)(ks + 2) * 32 * F2D;
      if ((ks & 1) == 0) { b0A = ldnt4(bp); b1A = ldnt4(bp + F2D); }
      else               { b0B = ldnt4(bp); b1B = ldnt4(bp + F2D); }
      unsigned short* Adst = AldsL + nx2 * 8192 + aofs;
#pragma unroll
      for (int j = 0; j < 4; ++j)
        async16(agp[j] + (ks + 2) * 32, Adst + j * 2048);
    }
    // 3) MFMA on current tile (compiler inserts lgkmcnt for af/bfr)
#pragma unroll
    for (int mi = 0; mi < 4; ++mi)
#pragma unroll
      for (int ni = 0; ni < 4; ++ni)
        acc[mi][ni] = __builtin_amdgcn_mfma_f32_16x16x32_bf16(af[mi], bfr[ni], acc[mi][ni], 0, 0, 0);
    // 4) counted wait: tile ks+1's 6 ops done (ks+2's 6 stay in flight); then store B(ks+1)
    if (ks < 30) {
      asm volatile("s_waitcnt vmcnt(6)" ::: "memory");
      __builtin_amdgcn_sched_barrier(0);
    } else if (ks == 30) {
      asm volatile("s_waitcnt vmcnt(0)" ::: "memory");
      __builtin_amdgcn_sched_barrier(0);
    }
    if (ks < 31) {
      // store from regs[(ks+1)&1]: ks even -> B-regs, ks odd -> A-regs
      fv4 b0 = (ks & 1) ? b0A : b0B;
      fv4 b1 = (ks & 1) ? b1A : b1B;
      BT_TRANSPOSE_STORE(BldsL + nx1 * 1024 + bofs)
      asm volatile("s_waitcnt lgkmcnt(0)" ::: "memory");
      __builtin_amdgcn_s_barrier();
      __builtin_amdgcn_sched_barrier(0);
    }
    // rotate buffers
    const int tmp = cur; cur = nx1; nx1 = nx2; nx2 = tmp;
  }

  // epilogue: +bgu, de-interleave gate/up via lane-pair shuffle, activation, store bf16
  const float* bguE = bgu + (size_t)e * F2D + ntile * 64;
#pragma unroll
  for (int mi = 0; mi < 4; ++mi) {
#pragma unroll
    for (int ni = 0; ni < 4; ++ni) {
      const int coll = ni * 16 + fr;
      const float bias = bguE[coll];
#pragma unroll
      for (int r = 0; r < 4; ++r) {
        const int srow = wv * 64 + mi * 16 + q * 4 + r;
        float v = acc[mi][ni][r] + bias;
        float pv = __shfl_xor(v, 1);
        float gate = (lane & 1) ? pv : v;   // even f2-cols are gate, odd are up
        float up   = (lane & 1) ? v : pv;
        gate = fminf(gate, LIMIT_C);
        up = fminf(fmaxf(up, -LIMIT_C), LIMIT_C);
        float glu = gate / (1.f + __expf(-ALPHA_C * gate));
        float val = (up + 1.f) * glu;
        if (!(lane & 1) && (mtile * 256 + srow) < Ne)
          Gact[(size_t)(base + srow) * ED + ((ntile * 64 + coll) >> 1)] = f2bf(val);
      }
    }
  }
}

// ---------------- GEMM2: round-4 proven config: block 256M x 64N, 512 thr, BK=32, dbuf ----------------
// A staged via async16 (LDS), B DPP-transposed [col][kpair] stride 20 dwords. Atomic epilogue.
// grid (16 ntiles, 2 mtiles, 16 experts).
#define BSTG2T 20
__global__ __launch_bounds__(512, 2) void k_gemm2(const unsigned short* __restrict__ Gact,
                                                  const float* __restrict__ Wd,
                                                  const int* __restrict__ cnt,
                                                  const int* __restrict__ off,
                                                  const int* __restrict__ gtok,
                                                  const float* __restrict__ gwt,
                                                  float* __restrict__ out) {
  const int e = blockIdx.z;
  const int Ne = cnt[e];
  const int mtile = blockIdx.y;
  if (mtile * 256 >= Ne) return;
  const int ntile = blockIdx.x;
  const int tid = threadIdx.x;          // 0..511
  const int lane = tid & 63;
  const int wv = tid >> 6;              // 0..7 (M 32-slice; N full 64)
  const int q = lane >> 4;
  const int fr = lane & 15;
  const int base = off[e] + mtile * 256;

  __shared__ unsigned short Alds[2][256 * 32];     // 32 KB
  __shared__ unsigned int Blds[2][64 * BSTG2T];    // transposed B, ~10.2 KB

  // A staging: wave wv stages rows wv*32 + (lane>>2) and +16; chunk = lane&3
  const int ar0 = wv * 32 + (lane >> 2);
  const unsigned short* agp0 = Gact + (size_t)(base + ar0) * ED + (lane & 3) * 8;
  const unsigned short* agp1 = agp0 + (size_t)16 * ED;
  const int aofs = wv * 1024;  // shorts: 32 rows * 32 shorts

  // B staging (waves 0..3): sub = lane&3; kpair = wv*4+sub; cols (lane>>2)*4..+3
  const int sub = lane & 3;
  const float* Wb = Wd + (size_t)e * ED * HD + (size_t)(2 * (wv * 4 + sub)) * HD + ntile * 64 + (lane >> 2) * 4;
  const int bofs = lane * BSTG2T + wv * 4;

  f32x4 acc[2][4] = {};
  fv4 b0, b1;

  if (tid < 256) {
    b0 = ldnt4(Wb);
    b1 = ldnt4(Wb + HD);
  }
  async16(agp0, Alds[0] + aofs);
  async16(agp1, Alds[0] + aofs + 512);
  if (tid < 256) BT_TRANSPOSE_STORE(Blds[0] + bofs)
  __syncthreads();

  for (int ks = 0; ks < 32; ++ks) {
    const int cur = ks & 1, nxt = cur ^ 1;
    const bool more = (ks + 1) < 32;
    if (more) {
      if (tid < 256) {
        const float* bp = Wb + (size_t)(ks + 1) * 32 * HD;
        b0 = ldnt4(bp);
        b1 = ldnt4(bp + HD);
      }
      async16(agp0 + (ks + 1) * 32, Alds[nxt] + aofs);
      async16(agp1 + (ks + 1) * 32, Alds[nxt] + aofs + 512);
    }
    short8 af[2], bfr[4];
#pragma unroll
    for (int mi = 0; mi < 2; ++mi)
      af[mi] = *(const short8*)(Alds[cur] + (wv * 32 + mi * 16 + fr) * 32 + q * 8);
#pragma unroll
    for (int ni = 0; ni < 4; ++ni)
      bfr[ni] = *(const short8*)(Blds[cur] + (ni * 16 + fr) * BSTG2T + q * 4);
#pragma unroll
    for (int mi = 0; mi < 2; ++mi)
#pragma unroll
      for (int ni = 0; ni < 4; ++ni)
        acc[mi][ni] = __builtin_amdgcn_mfma_f32_16x16x32_bf16(af[mi], bfr[ni], acc[mi][ni], 0, 0, 0);
    if (more && tid < 256) BT_TRANSPOSE_STORE(Blds[nxt] + bofs)
    __syncthreads();
  }

  // epilogue: weighted atomic accumulation into out (bd already pre-mixed by router)
#pragma unroll
  for (int mi = 0; mi < 2; ++mi) {
#pragma unroll
    for (int r = 0; r < 4; ++r) {
      const int srow = wv * 32 + mi * 16 + q * 4 + r;
      if ((mtile * 256 + srow) < Ne) {
        const int gsl = base + srow;
        const int tok = gtok[gsl];
        const float wt = gwt[gsl];
        float* op = out + (size_t)tok * HD + ntile * 64;
#pragma unroll
        for (int ni = 0; ni < 4; ++ni) {
          const int col = ni * 16 + fr;
          atomicAdd(op + col, wt * acc[mi][ni][r]);
        }
      }
    }
  }
}

extern "C" void kernel_launch(void* const* d_in, const int* in_sizes, int n_in,
                              void* d_out, int out_size, void* d_ws, size_t ws_size,
                              hipStream_t stream) {
  const float* x   = (const float*)d_in[0];
  const float* Wg  = (const float*)d_in[1];
  const float* bg  = (const float*)d_in[2];
  const float* Wgu = (const float*)d_in[3];
  const float* bgu = (const float*)d_in[4];
  const float* Wd  = (const float*)d_in[5];
  const float* bd  = (const float*)d_in[6];
  float* out = (float*)d_out;

  int* cnt = (int*)d_ws;                    // 16
  int* off = cnt + 16;                      // 16
  int* e01 = off + 16;                      // 1024
  float* w0f = (float*)(e01 + NT);          // 1024
  float* w1f = w0f + NT;                    // 1024
  int* gtok = (int*)(w1f + NT);             // GROWS
  float* gwt = (float*)(gtok + GROWS);      // GROWS
  unsigned short* Xbf = (unsigned short*)(gwt + GROWS);        // NT*HD bf16
  unsigned short* Gact = Xbf + (size_t)NT * HD;                // GROWS*ED bf16

  k_router<<<NT, 256, 0, stream>>>(x, Wg, bg, bd, e01, w0f, w1f, Xbf, out);
  k_scan<<<1, NT, 0, stream>>>(e01, w0f, w1f, cnt, off, gtok, gwt);
  k_gemm1<<<dim3(32, 2, NEXPERT), 256, 0, stream>>>(Xbf, Wgu, bgu, cnt, off, gtok, Gact);
  k_gemm2<<<dim3(16, 2, NEXPERT), 512, 0, stream>>>(Gact, Wd, cnt, off, gtok, gwt, out);
}